// Round 14
// baseline (223.903 us; speedup 1.0000x reference)
//
#include <hip/hip_runtime.h>
#include <math.h>

static const int NT = 50000, NDAT = 20000, NDEV = 4;
static const int EDT = 800000, EVT = 200000, ETT = 400000;

// scan geometry: 3 graphs x 25 tiles of 2048 (256 thr x 8 elems)
static const int SCAN_TILE = 2048, SCAN_NB = 25;
static const int DEG_STRIDE = 3 * NT;        // one histogram copy = 150000 ints

// fused-front kernel: histogram FIRST (latency-bound waves overlap with compute), then inputs
static const int HT   = EDT + EVT + ETT;     // 1,400,000 hist threads (1 edge each)
static const int IN_A = HT + NDAT * 128;     // conv1 messages, bf16
static const int IN_B = IN_A + NDAT * 4;     // as1
static const int IN_C = IN_B + NT * 4;       // ad1/ad2 (fused)
static const int IN_D = IN_C + NDEV * 128;   // hs2 (fp32)
static const int IN_E = IN_D + NDEV * 4;     // as2
static const int IN_F = IN_E + 256 * 128;    // w3 hi/lo split
static const int FRONT_N = IN_F;

// ---------------- workspace layout (float offsets), liveness-aliased ----------------
// Region R = [OFF_HS, OFF_HS+6.4M): pre-gemm rank/hsb1/rec1; then hsb3 (gemm epilogue).
static const size_t OFF_TASKS = 0;                   // 12,800,000  [NT,256] fp32
static const size_t OFF_HS    = 12800000;            //  6,400,000  region R
static const size_t OFF_RANK  = OFF_HS;              //  1,400,000 ints (dead after permute_w)
static const size_t OFF_HSB1  = OFF_HS + 1400000;    //  1,280,000 floats = 2.56M ushorts
static const size_t OFF_REC1  = OFF_HS + 2680000;    //  3,200,000 floats (800k x 16B) [ends 5,880,000]
static const size_t OFF_HSB3  = OFF_HS;              //  3,200,000 floats = 6.4M ushorts (gemm epilogue)
static const size_t OFF_REC2  = 19200000;            //    800,000 floats (200k x 16B)
static const size_t OFF_REC3  = 20000000;            //  1,600,000 floats (400k x 16B)
static const size_t OFF_DEG8  = 21600000;            //  1,200,000 ints: 8 XCD-private hists; becomes base8 in place
static const size_t OFF_RP    = 23350000;            //    150,003  3 x (NT+1) ints
static const size_t OFF_AS1   = 23500004;            //     80,000
static const size_t OFF_AD1   = 23580004;            //    200,000  as3 reuses
static const size_t OFF_AD2   = 23780004;            //    200,000  ad3 reuses
static const size_t OFF_HS2   = 23980004;            //        512
static const size_t OFF_AS2   = 23980516;            //         16
static const size_t OFF_QS1   = 23980532;            //         32
static const size_t OFF_QD1   = 23980564;            //         64
static const size_t OFF_P1    = 23980628;            //         32
static const size_t OFF_QS2   = 23980660;            //         32
static const size_t OFF_QD2   = 23980692;            //         64
static const size_t OFF_P2    = 23980756;            //         24
static const size_t OFF_P3    = 23980780;            //         16
static const size_t OFF_BSUM  = 23980796;            //        128 ints (75 used, RAW tile sums)
static const size_t OFF_W3HT  = 23980924;            //     16,384 (32768 ushorts, [128n][256k])
static const size_t OFF_W3LT  = 23997308;            //     16,384
static const size_t WS_TOTAL  = 24013692;            // floats (~96 MiB)

typedef short v8s __attribute__((ext_vector_type(8)));
typedef float v4f __attribute__((ext_vector_type(4)));

__device__ __forceinline__ float lrelu(float a) { return a > 0.f ? a : 0.2f * a; }
__device__ __forceinline__ unsigned short f2bf(float x) {
    unsigned int u = __float_as_uint(x);
    return (unsigned short)((u + 0x7FFFu + ((u >> 16) & 1u)) >> 16);
}
__device__ __forceinline__ float bf2f(unsigned short h) {
    return __uint_as_float(((unsigned int)h) << 16);
}
// select the h-th bf16 from the pair of packed words (w0|w1<<16, w2|w3<<16)
__device__ __forceinline__ float bfsel(unsigned int lo01, unsigned int lo23, int h) {
    unsigned int word = (h < 2) ? lo01 : lo23;
    return bf2f((unsigned short)((h & 1) ? (word >> 16) : (word & 0xFFFFu)));
}
__device__ __forceinline__ void cvt_split(const float4& A, const float4& B, v8s& hi, v8s& lo) {
    union { unsigned short u[8]; v8s v; } H, L;
    float f[8] = {A.x, A.y, A.z, A.w, B.x, B.y, B.z, B.w};
    #pragma unroll
    for (int i = 0; i < 8; ++i) {
        unsigned short h = f2bf(f[i]);
        H.u[i] = h;
        L.u[i] = f2bf(f[i] - bf2f(h));
    }
    hi = H.v; lo = L.v;
}

// Q[k][h] = sum_c W[k*128 + h*32 + c] * A[h*32 + c], for all 7 small matrices
__global__ void k_proj_small(const float* Ws1, const float* As1,
                             const float* Wd1, const float* Ad1,
                             const float* We1, const float* Ae1,
                             const float* Ws2, const float* As2,
                             const float* Wd2, const float* Ad2,
                             const float* We2, const float* Ae2,
                             const float* We3, const float* Ae3,
                             float* Qs1, float* Qd1, float* P1,
                             float* Qs2, float* Qd2, float* P2, float* P3) {
    int t = threadIdx.x;
    const float *W, *A; float* O; int u;
    if      (t < 32)  { W = Ws1; A = As1; O = Qs1; u = t; }
    else if (t < 96)  { W = Wd1; A = Ad1; O = Qd1; u = t - 32; }
    else if (t < 128) { W = We1; A = Ae1; O = P1;  u = t - 96; }
    else if (t < 160) { W = Ws2; A = As2; O = Qs2; u = t - 128; }
    else if (t < 224) { W = Wd2; A = Ad2; O = Qd2; u = t - 160; }
    else if (t < 248) { W = We2; A = Ae2; O = P2;  u = t - 224; }
    else if (t < 264) { W = We3; A = Ae3; O = P3;  u = t - 248; }
    else return;
    int k = u >> 2, h = u & 3;
    float acc = 0.f;
    for (int c = 0; c < 32; ++c) acc += W[k * 128 + h * 32 + c] * A[h * 32 + c];
    O[k * 4 + h] = acc;
}

// fused front: 1-edge-per-thread histogram FIRST into the wave's XCD-private copy
// (workgroup-scope atomics stay in the local XCD L2 -> no fabric write-through),
// then inputs prep (conv1 bf16 msgs, as1, ad1/ad2, hs2, as2, W3 split).
__global__ __launch_bounds__(256) void k_front(const float* __restrict__ x_data,
                                               const float* __restrict__ Ws1,
                                               unsigned short* __restrict__ hsb1,
                                               const float* __restrict__ Qs1,
                                               float* __restrict__ as1,
                                               const float* __restrict__ x_tasks,
                                               const float* __restrict__ Qd1,
                                               const float* __restrict__ Qd2,
                                               float* __restrict__ ad1, float* __restrict__ ad2,
                                               const float* __restrict__ x_dev,
                                               const float* __restrict__ Ws2,
                                               float* __restrict__ hs2,
                                               const float* __restrict__ Qs2,
                                               float* __restrict__ as2,
                                               const float* __restrict__ W3,
                                               unsigned short* __restrict__ w3hT,
                                               unsigned short* __restrict__ w3lT,
                                               const int* __restrict__ dt,
                                               const int* __restrict__ vt,
                                               const int* __restrict__ tt,
                                               int* __restrict__ deg8,
                                               int* __restrict__ rank) {
    int idx = blockIdx.x * blockDim.x + threadIdx.x;
    if (idx < HT) {                          // histogram, 1 edge/thread, XCD-private copy
        unsigned int xcc;
        asm volatile("s_getreg_b32 %0, hwreg(20, 0, 32)" : "=s"(xcc));  // HW_REG_XCC_ID
        xcc &= 7u;
        int* dg = deg8 + (size_t)xcc * DEG_STRIDE;
        int r;
        if (idx < EDT) {
            r = __hip_atomic_fetch_add(&dg[dt[EDT + idx]], 1,
                                       __ATOMIC_RELAXED, __HIP_MEMORY_SCOPE_WORKGROUP);
            rank[idx] = (r << 3) | (int)xcc;
        } else if (idx < EDT + EVT) {
            r = __hip_atomic_fetch_add(&dg[NT + vt[EVT + (idx - EDT)]], 1,
                                       __ATOMIC_RELAXED, __HIP_MEMORY_SCOPE_WORKGROUP);
            rank[idx] = (r << 3) | (int)xcc;
        } else {
            r = __hip_atomic_fetch_add(&dg[2 * NT + tt[ETT + (idx - EDT - EVT)]], 1,
                                       __ATOMIC_RELAXED, __HIP_MEMORY_SCOPE_WORKGROUP);
            rank[idx] = (r << 3) | (int)xcc;
        }
    } else if (idx < IN_A) {                 // conv1 message table, bf16
        int i = idx - HT;
        int n = i >> 7, j = i & 127;
        float acc = 0.f;
        #pragma unroll
        for (int k = 0; k < 8; ++k) acc += x_data[n * 8 + k] * Ws1[k * 128 + j];
        hsb1[i] = f2bf(acc);
    } else if (idx < IN_B) {                 // as1
        int i = idx - IN_A;
        int n = i >> 2, h = i & 3;
        float acc = 0.f;
        #pragma unroll
        for (int k = 0; k < 8; ++k) acc += x_data[n * 8 + k] * Qs1[k * 4 + h];
        as1[i] = acc;
    } else if (idx < IN_C) {                 // ad1, ad2 (one pass over x_tasks)
        int i = idx - IN_B;
        int n = i >> 2, h = i & 3;
        float a = 0.f, b = 0.f;
        #pragma unroll
        for (int k = 0; k < 16; ++k) {
            float v = x_tasks[n * 16 + k];
            a += v * Qd1[k * 4 + h];
            b += v * Qd2[k * 4 + h];
        }
        ad1[i] = a; ad2[i] = b;
    } else if (idx < IN_D) {                 // hs2 (fp32)
        int i = idx - IN_C;
        int n = i >> 7, j = i & 127;
        float acc = 0.f;
        #pragma unroll
        for (int k = 0; k < 8; ++k) acc += x_dev[n * 8 + k] * Ws2[k * 128 + j];
        hs2[i] = acc;
    } else if (idx < IN_E) {                 // as2
        int i = idx - IN_D;
        int n = i >> 2, h = i & 3;
        float acc = 0.f;
        #pragma unroll
        for (int k = 0; k < 8; ++k) acc += x_dev[n * 8 + k] * Qs2[k * 4 + h];
        as2[i] = acc;
    } else if (idx < IN_F) {                 // W3 split, transposed
        int i = idx - IN_E;
        int k = i >> 7, n = i & 127;
        float x = W3[i];
        unsigned short h = f2bf(x);
        w3hT[n * 256 + k] = h;
        w3lT[n * 256 + k] = f2bf(x - bf2f(h));
    }
}

// scan phase A: per-tile block reduce over the SUM of 8 copies -> bsum[75]
__global__ __launch_bounds__(256) void k_scan_part(const int* __restrict__ deg8,
                                                   int* __restrict__ bsum) {
    int b = blockIdx.x;
    int g = b / SCAN_NB, t = b % SCAN_NB;
    int base = t * SCAN_TILE + threadIdx.x * 8;
    const int* dg = deg8 + (size_t)g * NT;
    int s = 0;
    #pragma unroll
    for (int x = 0; x < 8; ++x) {
        const int* dx = dg + (size_t)x * DEG_STRIDE;
        if (base + 8 <= NT) {
            int4 a = *reinterpret_cast<const int4*>(dx + base);
            int4 c = *reinterpret_cast<const int4*>(dx + base + 4);
            s += a.x + a.y + a.z + a.w + c.x + c.y + c.z + c.w;
        } else {
            for (int i = 0; i < 8; ++i) if (base + i < NT) s += dx[base + i];
        }
    }
    __shared__ int red[256];
    red[threadIdx.x] = s;
    __syncthreads();
    for (int off = 128; off > 0; off >>= 1) {
        if (threadIdx.x < off) red[threadIdx.x] += red[threadIdx.x + off];
        __syncthreads();
    }
    if (threadIdx.x == 0) bsum[b] = red[0];
}

// scan phase B: per-tile exclusive scan of per-dst TOTALS (+bsum prefix); writes rp
// and converts deg8 IN PLACE to absolute per-copy bases: base8[x][d] = rp[d]+sum_{x'<x}.
__global__ __launch_bounds__(256) void k_scan_final(int* __restrict__ deg8,
                                                    const int* __restrict__ bsum,
                                                    int* __restrict__ rp) {
    int b = blockIdx.x;
    int g = b / SCAN_NB, t = b % SCAN_NB;
    int tid = threadIdx.x;
    int base = t * SCAN_TILE + tid * 8;
    int* dg = deg8 + (size_t)g * NT;
    int* rpg = rp + (size_t)g * (NT + 1);
    int c[8][8];
    int v[8];
    int s = 0;
    #pragma unroll
    for (int i = 0; i < 8; ++i) {
        int idx = base + i;
        int tot = 0;
        #pragma unroll
        for (int x = 0; x < 8; ++x) {
            int val = (idx < NT) ? dg[(size_t)x * DEG_STRIDE + idx] : 0;
            c[i][x] = val; tot += val;
        }
        v[i] = tot; s += tot;
    }
    __shared__ int sums[256];
    sums[tid] = s;
    __syncthreads();
    for (int off = 1; off < 256; off <<= 1) {
        int x = (tid >= off) ? sums[tid - off] : 0;
        __syncthreads();
        sums[tid] += x;
        __syncthreads();
    }
    int toff = 0;
    for (int t2 = 0; t2 < t; ++t2) toff += bsum[g * SCAN_NB + t2];
    int run = toff + (tid ? sums[tid - 1] : 0);
    #pragma unroll
    for (int i = 0; i < 8; ++i) {
        int idx = base + i;
        if (idx < NT) {
            rpg[idx] = run;
            int bb = run;
            #pragma unroll
            for (int x = 0; x < 8; ++x) {
                dg[(size_t)x * DEG_STRIDE + idx] = bb;
                bb += c[i][x];
            }
            run += v[i];
            if (idx == NT - 1) rpg[NT] = run;
        }
    }
}

// permute + weight precompute: ONE 16B scattered record per edge; slot from XCD-base.
// conv1/conv2: {w0..w3 bf16 (8B), src, pad}; conv3: {src, ae0..ae3 bf16 (8B), pad}.
__global__ void k_permute_w(const int* __restrict__ dt, const int* __restrict__ vt,
                            const int* __restrict__ tt, const int* __restrict__ rank,
                            const int* __restrict__ base8,
                            const float* __restrict__ as1, const float* __restrict__ ad1,
                            const float* __restrict__ P1, const float* __restrict__ ea1,
                            const float* __restrict__ as2, const float* __restrict__ ad2,
                            const float* __restrict__ P2, const float* __restrict__ ea2,
                            const float* __restrict__ P3, const float* __restrict__ ea3,
                            uint4* __restrict__ rec1, uint4* __restrict__ rec2,
                            uint4* __restrict__ rec3) {
    int e = blockIdx.x * blockDim.x + threadIdx.x;
    if (e < EDT) {
        int s = dt[e], d = dt[EDT + e];
        int rk = rank[e];
        int slot = base8[(size_t)(rk & 7) * DEG_STRIDE + d] + (rk >> 3);
        float l[4];
        #pragma unroll
        for (int h = 0; h < 4; ++h) l[h] = as1[s * 4 + h] + ad1[d * 4 + h];
        float4 A = *reinterpret_cast<const float4*>(&ea1[(size_t)e * 8]);
        float4 B = *reinterpret_cast<const float4*>(&ea1[(size_t)e * 8 + 4]);
        float ev[8] = {A.x, A.y, A.z, A.w, B.x, B.y, B.z, B.w};
        #pragma unroll
        for (int k = 0; k < 8; ++k)
            #pragma unroll
            for (int h = 0; h < 4; ++h) l[h] += ev[k] * P1[k * 4 + h];
        unsigned int w01 = (unsigned int)f2bf(expf(lrelu(l[0])))
                         | ((unsigned int)f2bf(expf(lrelu(l[1]))) << 16);
        unsigned int w23 = (unsigned int)f2bf(expf(lrelu(l[2])))
                         | ((unsigned int)f2bf(expf(lrelu(l[3]))) << 16);
        rec1[slot] = make_uint4(w01, w23, (unsigned int)s, 0u);
    } else if (e < EDT + EVT) {
        int ee = e - EDT;
        int s = vt[ee], d = vt[EVT + ee];
        int rk = rank[e];
        int slot = base8[(size_t)(rk & 7) * DEG_STRIDE + NT + d] + (rk >> 3);
        float l[4];
        #pragma unroll
        for (int h = 0; h < 4; ++h) l[h] = as2[s * 4 + h] + ad2[d * 4 + h];
        float2 a = *reinterpret_cast<const float2*>(&ea2[(size_t)ee * 6]);
        float2 b = *reinterpret_cast<const float2*>(&ea2[(size_t)ee * 6 + 2]);
        float2 c = *reinterpret_cast<const float2*>(&ea2[(size_t)ee * 6 + 4]);
        float ev[6] = {a.x, a.y, b.x, b.y, c.x, c.y};
        #pragma unroll
        for (int k = 0; k < 6; ++k)
            #pragma unroll
            for (int h = 0; h < 4; ++h) l[h] += ev[k] * P2[k * 4 + h];
        unsigned int w01 = (unsigned int)f2bf(expf(lrelu(l[0])))
                         | ((unsigned int)f2bf(expf(lrelu(l[1]))) << 16);
        unsigned int w23 = (unsigned int)f2bf(expf(lrelu(l[2])))
                         | ((unsigned int)f2bf(expf(lrelu(l[3]))) << 16);
        rec2[slot] = make_uint4(w01, w23, (unsigned int)s, 0u);
    } else if (e < EDT + EVT + ETT) {
        int ee = e - EDT - EVT;
        int s = tt[ee], d = tt[ETT + ee];
        int rk = rank[e];
        int slot = base8[(size_t)(rk & 7) * DEG_STRIDE + 2 * NT + d] + (rk >> 3);
        float4 q = *reinterpret_cast<const float4*>(&ea3[(size_t)ee * 4]);
        float ae[4];
        #pragma unroll
        for (int h = 0; h < 4; ++h)
            ae[h] = q.x * P3[h] + q.y * P3[4 + h] + q.z * P3[8 + h] + q.w * P3[12 + h];
        unsigned int a01 = (unsigned int)f2bf(ae[0]) | ((unsigned int)f2bf(ae[1]) << 16);
        unsigned int a23 = (unsigned int)f2bf(ae[2]) | ((unsigned int)f2bf(ae[3]) << 16);
        rec3[slot] = make_uint4((unsigned int)s, a01, a23, 0u);
    }
}

// fused conv1+conv2 gathers: block < NT/8 -> conv1 (bf16 msgs); else conv2 (fp32 2KB table)
__global__ __launch_bounds__(256) void k_gather12(const int* __restrict__ rp1,
                                                  const uint4* __restrict__ rec1,
                                                  const unsigned short* __restrict__ hsb,
                                                  const float* __restrict__ b1,
                                                  const int* __restrict__ rp2,
                                                  const uint4* __restrict__ rec2,
                                                  const float* __restrict__ hs2,
                                                  const float* __restrict__ b2,
                                                  float* __restrict__ tasks) {
    int tid = threadIdx.x;
    int lane = tid & 31;
    int h = lane >> 3;
    if (blockIdx.x < NT / 8) {
        int d = blockIdx.x * 8 + (tid >> 5);
        int c0 = (lane & 7) * 4;
        int i0 = rp1[d], i1 = rp1[d + 1];
        float a0 = 0.f, a1 = 0.f, a2 = 0.f, a3 = 0.f, den = 0.f;
        int i = i0;
        for (; i + 4 <= i1; i += 4) {
            uint4 r0 = rec1[i], r1 = rec1[i + 1], r2 = rec1[i + 2], r3 = rec1[i + 3];
            float w0 = bfsel(r0.x, r0.y, h);
            float w1 = bfsel(r1.x, r1.y, h);
            float w2 = bfsel(r2.x, r2.y, h);
            float w3 = bfsel(r3.x, r3.y, h);
            ushort4 m0 = *reinterpret_cast<const ushort4*>(&hsb[(size_t)r0.z * 128 + h * 32 + c0]);
            ushort4 m1 = *reinterpret_cast<const ushort4*>(&hsb[(size_t)r1.z * 128 + h * 32 + c0]);
            ushort4 m2 = *reinterpret_cast<const ushort4*>(&hsb[(size_t)r2.z * 128 + h * 32 + c0]);
            ushort4 m3 = *reinterpret_cast<const ushort4*>(&hsb[(size_t)r3.z * 128 + h * 32 + c0]);
            a0 += w0 * bf2f(m0.x) + w1 * bf2f(m1.x) + w2 * bf2f(m2.x) + w3 * bf2f(m3.x);
            a1 += w0 * bf2f(m0.y) + w1 * bf2f(m1.y) + w2 * bf2f(m2.y) + w3 * bf2f(m3.y);
            a2 += w0 * bf2f(m0.z) + w1 * bf2f(m1.z) + w2 * bf2f(m2.z) + w3 * bf2f(m3.z);
            a3 += w0 * bf2f(m0.w) + w1 * bf2f(m1.w) + w2 * bf2f(m2.w) + w3 * bf2f(m3.w);
            den += w0 + w1 + w2 + w3;
        }
        for (; i < i1; ++i) {
            uint4 r = rec1[i];
            float w = bfsel(r.x, r.y, h);
            ushort4 m = *reinterpret_cast<const ushort4*>(&hsb[(size_t)r.z * 128 + h * 32 + c0]);
            a0 += w * bf2f(m.x); a1 += w * bf2f(m.y);
            a2 += w * bf2f(m.z); a3 += w * bf2f(m.w);
            den += w;
        }
        int j0 = h * 32 + c0;
        float4 b4 = *reinterpret_cast<const float4*>(&b1[j0]);
        float r = 1.f / (den + 1e-16f);
        float4 o = make_float4(fmaxf(a0 * r + b4.x, 0.f), fmaxf(a1 * r + b4.y, 0.f),
                               fmaxf(a2 * r + b4.z, 0.f), fmaxf(a3 * r + b4.w, 0.f));
        *reinterpret_cast<float4*>(&tasks[(size_t)d * 256 + j0]) = o;
    } else {
        int d = (blockIdx.x - NT / 8) * 8 + (tid >> 5);
        int i0 = rp2[d], i1 = rp2[d + 1];
        float ax = 0.f, ay = 0.f, az = 0.f, aw = 0.f, den = 0.f;
        int i = i0;
        for (; i + 4 <= i1; i += 4) {
            uint4 r0 = rec2[i], r1 = rec2[i + 1], r2 = rec2[i + 2], r3 = rec2[i + 3];
            float w0 = bfsel(r0.x, r0.y, h);
            float w1 = bfsel(r1.x, r1.y, h);
            float w2 = bfsel(r2.x, r2.y, h);
            float w3 = bfsel(r3.x, r3.y, h);
            float4 v0 = *reinterpret_cast<const float4*>(&hs2[r0.z * 128 + lane * 4]);
            float4 v1 = *reinterpret_cast<const float4*>(&hs2[r1.z * 128 + lane * 4]);
            float4 v2 = *reinterpret_cast<const float4*>(&hs2[r2.z * 128 + lane * 4]);
            float4 v3 = *reinterpret_cast<const float4*>(&hs2[r3.z * 128 + lane * 4]);
            ax += v0.x * w0 + v1.x * w1 + v2.x * w2 + v3.x * w3;
            ay += v0.y * w0 + v1.y * w1 + v2.y * w2 + v3.y * w3;
            az += v0.z * w0 + v1.z * w1 + v2.z * w2 + v3.z * w3;
            aw += v0.w * w0 + v1.w * w1 + v2.w * w2 + v3.w * w3;
            den += w0 + w1 + w2 + w3;
        }
        for (; i < i1; ++i) {
            uint4 r4 = rec2[i];
            float w = bfsel(r4.x, r4.y, h);
            float4 v = *reinterpret_cast<const float4*>(&hs2[r4.z * 128 + lane * 4]);
            ax += v.x * w; ay += v.y * w; az += v.z * w; aw += v.w * w;
            den += w;
        }
        float4 b4 = *reinterpret_cast<const float4*>(&b2[lane * 4]);
        float r = 1.f / (den + 1e-16f);
        float4 o = make_float4(fmaxf(ax * r + b4.x, 0.f), fmaxf(ay * r + b4.y, 0.f),
                               fmaxf(az * r + b4.z, 0.f), fmaxf(aw * r + b4.w, 0.f));
        *reinterpret_cast<float4*>(&tasks[(size_t)d * 256 + 128 + lane * 4]) = o;
    }
}

// conv3 gather: 16B records carry {src, ae bf16}; per-head softmax + self-loop
// (mean ae); head-mean via shfl_xor; +b3, relu fused. Writes d_out once.
__global__ __launch_bounds__(256) void k_gather_c3(const int* __restrict__ rp,
                                                   const uint4* __restrict__ rec,
                                                   const float* __restrict__ as3,
                                                   const float* __restrict__ ad3,
                                                   const unsigned short* __restrict__ hsb,
                                                   const float* __restrict__ b3,
                                                   float* __restrict__ out) {
    int tid = threadIdx.x;
    int d = blockIdx.x * 8 + (tid >> 5);
    int lane = tid & 31;
    int h = lane >> 3;
    int c0 = (lane & 7) * 4;
    float adv = ad3[d * 4 + h];
    int i0 = rp[d], i1 = rp[d + 1];
    float a0 = 0.f, a1 = 0.f, a2 = 0.f, a3 = 0.f, den = 0.f, aes = 0.f;
    int i = i0;
    for (; i + 4 <= i1; i += 4) {
        uint4 r0 = rec[i], r1 = rec[i + 1], r2 = rec[i + 2], r3 = rec[i + 3];
        float s0 = as3[(size_t)r0.x * 4 + h], s1 = as3[(size_t)r1.x * 4 + h];
        float s2 = as3[(size_t)r2.x * 4 + h], s3 = as3[(size_t)r3.x * 4 + h];
        ushort4 m0 = *reinterpret_cast<const ushort4*>(&hsb[(size_t)r0.x * 128 + h * 32 + c0]);
        ushort4 m1 = *reinterpret_cast<const ushort4*>(&hsb[(size_t)r1.x * 128 + h * 32 + c0]);
        ushort4 m2 = *reinterpret_cast<const ushort4*>(&hsb[(size_t)r2.x * 128 + h * 32 + c0]);
        ushort4 m3 = *reinterpret_cast<const ushort4*>(&hsb[(size_t)r3.x * 128 + h * 32 + c0]);
        float ae0 = bfsel(r0.y, r0.z, h);
        float ae1 = bfsel(r1.y, r1.z, h);
        float ae2 = bfsel(r2.y, r2.z, h);
        float ae3 = bfsel(r3.y, r3.z, h);
        float w0 = expf(lrelu(s0 + adv + ae0));
        float w1 = expf(lrelu(s1 + adv + ae1));
        float w2 = expf(lrelu(s2 + adv + ae2));
        float w3 = expf(lrelu(s3 + adv + ae3));
        a0 += w0 * bf2f(m0.x) + w1 * bf2f(m1.x) + w2 * bf2f(m2.x) + w3 * bf2f(m3.x);
        a1 += w0 * bf2f(m0.y) + w1 * bf2f(m1.y) + w2 * bf2f(m2.y) + w3 * bf2f(m3.y);
        a2 += w0 * bf2f(m0.z) + w1 * bf2f(m1.z) + w2 * bf2f(m2.z) + w3 * bf2f(m3.z);
        a3 += w0 * bf2f(m0.w) + w1 * bf2f(m1.w) + w2 * bf2f(m2.w) + w3 * bf2f(m3.w);
        den += w0 + w1 + w2 + w3;
        aes += ae0 + ae1 + ae2 + ae3;
    }
    for (; i < i1; ++i) {
        uint4 r4 = rec[i];
        float s = as3[(size_t)r4.x * 4 + h];
        ushort4 m = *reinterpret_cast<const ushort4*>(&hsb[(size_t)r4.x * 128 + h * 32 + c0]);
        float ae = bfsel(r4.y, r4.z, h);
        float w = expf(lrelu(s + adv + ae));
        a0 += w * bf2f(m.x); a1 += w * bf2f(m.y);
        a2 += w * bf2f(m.z); a3 += w * bf2f(m.w);
        den += w; aes += ae;
    }
    float cnt = (float)(i1 - i0);
    float mloop = aes / fmaxf(cnt, 1.f);
    float exl = expf(lrelu(as3[(size_t)d * 4 + h] + adv + mloop));
    ushort4 md = *reinterpret_cast<const ushort4*>(&hsb[(size_t)d * 128 + h * 32 + c0]);
    float rden = 1.f / (den + exl + 1e-16f);
    float p0 = (a0 + exl * bf2f(md.x)) * rden;
    float p1 = (a1 + exl * bf2f(md.y)) * rden;
    float p2 = (a2 + exl * bf2f(md.z)) * rden;
    float p3 = (a3 + exl * bf2f(md.w)) * rden;
    p0 += __shfl_xor(p0, 8, 32); p0 += __shfl_xor(p0, 16, 32);
    p1 += __shfl_xor(p1, 8, 32); p1 += __shfl_xor(p1, 16, 32);
    p2 += __shfl_xor(p2, 8, 32); p2 += __shfl_xor(p2, 16, 32);
    p3 += __shfl_xor(p3, 8, 32); p3 += __shfl_xor(p3, 16, 32);
    if ((lane >> 3) == 0) {
        float4 o;
        o.x = fmaxf(0.25f * p0 + b3[c0 + 0], 0.f);
        o.y = fmaxf(0.25f * p1 + b3[c0 + 1], 0.f);
        o.z = fmaxf(0.25f * p2 + b3[c0 + 2], 0.f);
        o.w = fmaxf(0.25f * p3 + b3[c0 + 3], 0.f);
        *reinterpret_cast<float4*>(&out[(size_t)d * 32 + c0]) = o;
    }
}

// hs3 = tasks @ W3 via bf16 split MFMA; epilogue writes hsb3 (bf16) and as3/ad3
// directly from accumulator registers (hs3 fp32 is never materialized).
__global__ __launch_bounds__(256, 2) void k_gemm_mfma(const float* __restrict__ T,
                                                      const unsigned short* __restrict__ w3hT,
                                                      const unsigned short* __restrict__ w3lT,
                                                      const float* __restrict__ As3,
                                                      const float* __restrict__ Ad3,
                                                      unsigned short* __restrict__ hsb,
                                                      float* __restrict__ as3o,
                                                      float* __restrict__ ad3o) {
    __shared__ uint4 sB[2][2048];      // [hi/lo][128 cols x 16 chunks], 64 KiB
    int tid = threadIdx.x;
    int lane = tid & 63;
    int arow = lane & 15;
    int kgrp = lane >> 4;
    int s0 = blockIdx.x * 8 + (tid >> 6) * 2;
    int ss0 = s0 < 3125 ? s0 : 3124;
    int ss1 = (s0 + 1) < 3125 ? (s0 + 1) : 3124;
    const uint4* w3h4 = reinterpret_cast<const uint4*>(w3hT);
    const uint4* w3l4 = reinterpret_cast<const uint4*>(w3lT);

    v4f acc[2][8];
    #pragma unroll
    for (int sp = 0; sp < 2; ++sp)
        #pragma unroll
        for (int nt = 0; nt < 8; ++nt) acc[sp][nt] = (v4f)0.f;

    #pragma unroll
    for (int kt = 0; kt < 2; ++kt) {
        __syncthreads();
        float4 a0[8], a1[8];
        const float* Ta0 = T + (size_t)(ss0 * 16 + arow) * 256 + kt * 128 + kgrp * 8;
        const float* Ta1 = T + (size_t)(ss1 * 16 + arow) * 256 + kt * 128 + kgrp * 8;
        #pragma unroll
        for (int kc = 0; kc < 4; ++kc) {
            a0[kc * 2]     = *reinterpret_cast<const float4*>(Ta0 + kc * 32);
            a0[kc * 2 + 1] = *reinterpret_cast<const float4*>(Ta0 + kc * 32 + 4);
            a1[kc * 2]     = *reinterpret_cast<const float4*>(Ta1 + kc * 32);
            a1[kc * 2 + 1] = *reinterpret_cast<const float4*>(Ta1 + kc * 32 + 4);
        }
        #pragma unroll
        for (int it = 0; it < 8; ++it) {
            int c = it * 256 + tid;
            int n = c >> 4, ch = c & 15;
            int gi = n * 32 + kt * 16 + ch;
            int li = n * 16 + (ch ^ (n & 7));
            sB[0][li] = w3h4[gi];
            sB[1][li] = w3l4[gi];
        }
        __syncthreads();
        #pragma unroll
        for (int kc = 0; kc < 4; ++kc) {
            v8s ah0, al0, ah1, al1;
            cvt_split(a0[kc * 2], a0[kc * 2 + 1], ah0, al0);
            cvt_split(a1[kc * 2], a1[kc * 2 + 1], ah1, al1);
            #pragma unroll
            for (int nt = 0; nt < 8; ++nt) {
                int col = nt * 16 + arow;
                int ch = kc * 4 + kgrp;
                int li = col * 16 + (ch ^ (col & 7));
                v8s bh = *reinterpret_cast<const v8s*>(&sB[0][li]);
                v8s bl = *reinterpret_cast<const v8s*>(&sB[1][li]);
                acc[0][nt] = __builtin_amdgcn_mfma_f32_16x16x32_bf16(ah0, bh, acc[0][nt], 0, 0, 0);
                acc[0][nt] = __builtin_amdgcn_mfma_f32_16x16x32_bf16(ah0, bl, acc[0][nt], 0, 0, 0);
                acc[0][nt] = __builtin_amdgcn_mfma_f32_16x16x32_bf16(al0, bh, acc[0][nt], 0, 0, 0);
                acc[1][nt] = __builtin_amdgcn_mfma_f32_16x16x32_bf16(ah1, bh, acc[1][nt], 0, 0, 0);
                acc[1][nt] = __builtin_amdgcn_mfma_f32_16x16x32_bf16(ah1, bl, acc[1][nt], 0, 0, 0);
                acc[1][nt] = __builtin_amdgcn_mfma_f32_16x16x32_bf16(al1, bh, acc[1][nt], 0, 0, 0);
            }
        }
    }
    // epilogue: bf16 messages + per-row as3/ad3 (16-lane shfl reduction per head)
    float As3v[8], Ad3v[8];
    #pragma unroll
    for (int nt = 0; nt < 8; ++nt) {
        As3v[nt] = As3[nt * 16 + arow];
        Ad3v[nt] = Ad3[nt * 16 + arow];
    }
    #pragma unroll
    for (int sp = 0; sp < 2; ++sp) {
        int s = s0 + sp;
        if (s >= 3125) continue;
        #pragma unroll
        for (int i = 0; i < 4; ++i) {
            int row = s * 16 + kgrp * 4 + i;
            #pragma unroll
            for (int nt = 0; nt < 8; ++nt)
                hsb[(size_t)row * 128 + nt * 16 + arow] = f2bf(acc[sp][nt][i]);
            #pragma unroll
            for (int h = 0; h < 4; ++h) {
                float pa = acc[sp][2 * h][i] * As3v[2 * h] + acc[sp][2 * h + 1][i] * As3v[2 * h + 1];
                float pb = acc[sp][2 * h][i] * Ad3v[2 * h] + acc[sp][2 * h + 1][i] * Ad3v[2 * h + 1];
                #pragma unroll
                for (int off = 1; off < 16; off <<= 1) {
                    pa += __shfl_xor(pa, off, 64);
                    pb += __shfl_xor(pb, off, 64);
                }
                if (arow == 0) {
                    as3o[row * 4 + h] = pa;
                    ad3o[row * 4 + h] = pb;
                }
            }
        }
    }
}

extern "C" void kernel_launch(void* const* d_in, const int* in_sizes, int n_in,
                              void* d_out, int out_size, void* d_ws, size_t ws_size,
                              hipStream_t stream) {
    const float* x_data  = (const float*)d_in[0];
    const float* x_tasks = (const float*)d_in[1];
    const float* x_dev   = (const float*)d_in[2];
    const int*   ei_dt   = (const int*)d_in[3];
    const float* ea_dt   = (const float*)d_in[4];
    const int*   ei_vt   = (const int*)d_in[5];
    const float* ea_vt   = (const float*)d_in[6];
    const int*   ei_tt   = (const int*)d_in[7];
    const float* ea_tt   = (const float*)d_in[8];
    const float* Ws1 = (const float*)d_in[9];  const float* Wd1 = (const float*)d_in[10];
    const float* We1 = (const float*)d_in[11]; const float* As1 = (const float*)d_in[12];
    const float* Ad1 = (const float*)d_in[13]; const float* Ae1 = (const float*)d_in[14];
    const float* b1  = (const float*)d_in[15];
    const float* Ws2 = (const float*)d_in[16]; const float* Wd2 = (const float*)d_in[17];
    const float* We2 = (const float*)d_in[18]; const float* As2 = (const float*)d_in[19];
    const float* Ad2 = (const float*)d_in[20]; const float* Ae2 = (const float*)d_in[21];
    const float* b2  = (const float*)d_in[22];
    const float* W3  = (const float*)d_in[23]; const float* We3 = (const float*)d_in[24];
    const float* As3 = (const float*)d_in[25]; const float* Ad3 = (const float*)d_in[26];
    const float* Ae3 = (const float*)d_in[27]; const float* b3  = (const float*)d_in[28];

    if (ws_size < WS_TOTAL * sizeof(float)) return;

    float* w = (float*)d_ws;
    float* tasks = w + OFF_TASKS;
    int*   rank  = (int*)(w + OFF_RANK);
    unsigned short* hsb1 = (unsigned short*)(w + OFF_HSB1);
    unsigned short* hsb3 = (unsigned short*)(w + OFF_HSB3);  // aliases rank/hsb1/rec1 (dead by gemm)
    uint4* rec1  = (uint4*)(w + OFF_REC1);
    uint4* rec2  = (uint4*)(w + OFF_REC2);
    uint4* rec3  = (uint4*)(w + OFF_REC3);
    int*   deg8  = (int*)(w + OFF_DEG8);     // 8 XCD-private hists; becomes base8 after scan
    int*   rp    = (int*)(w + OFF_RP);
    int*   bsum  = (int*)(w + OFF_BSUM);
    unsigned short* w3hT = (unsigned short*)(w + OFF_W3HT);
    unsigned short* w3lT = (unsigned short*)(w + OFF_W3LT);
    float* as1 = w + OFF_AS1;
    float* ad1 = w + OFF_AD1; float* as3 = w + OFF_AD1;   // as3 aliases ad1 (dead after permute)
    float* ad2 = w + OFF_AD2; float* ad3 = w + OFF_AD2;   // ad3 aliases ad2
    float* hs2 = w + OFF_HS2; float* as2 = w + OFF_AS2;
    float* Qs1 = w + OFF_QS1; float* Qd1 = w + OFF_QD1; float* P1 = w + OFF_P1;
    float* Qs2 = w + OFF_QS2; float* Qd2 = w + OFF_QD2; float* P2 = w + OFF_P2;
    float* P3  = w + OFF_P3;
    float* out = (float*)d_out;

    dim3 B(256);
    #define GRID(n) dim3((unsigned)(((n) + 255) / 256))

    hipMemsetAsync(deg8, 0, 8 * DEG_STRIDE * sizeof(int), stream);
    k_proj_small<<<1, 320, 0, stream>>>(Ws1, As1, Wd1, Ad1, We1, Ae1,
                                        Ws2, As2, Wd2, Ad2, We2, Ae2, We3, Ae3,
                                        Qs1, Qd1, P1, Qs2, Qd2, P2, P3);
    k_front<<<GRID(FRONT_N), B, 0, stream>>>(x_data, Ws1, hsb1, Qs1, as1,
                                             x_tasks, Qd1, Qd2, ad1, ad2,
                                             x_dev, Ws2, hs2, Qs2, as2,
                                             W3, w3hT, w3lT,
                                             ei_dt, ei_vt, ei_tt, deg8, rank);
    k_scan_part<<<dim3(3 * SCAN_NB), B, 0, stream>>>(deg8, bsum);
    k_scan_final<<<dim3(3 * SCAN_NB), B, 0, stream>>>(deg8, bsum, rp);
    k_permute_w<<<GRID(EDT + EVT + ETT), B, 0, stream>>>(ei_dt, ei_vt, ei_tt, rank, deg8,
                                                         as1, ad1, P1, ea_dt,
                                                         as2, ad2, P2, ea_vt,
                                                         P3, ea_tt,
                                                         rec1, rec2, rec3);
    k_gather12<<<dim3(2 * (NT / 8)), B, 0, stream>>>(rp, rec1, hsb1, b1,
                                                     rp + (NT + 1), rec2, hs2, b2, tasks);
    k_gemm_mfma<<<dim3(391), dim3(256), 0, stream>>>(tasks, w3hT, w3lT, As3, Ad3,
                                                     hsb3, as3, ad3);
    k_gather_c3<<<dim3(NT / 8), B, 0, stream>>>(rp + 2 * (NT + 1), rec3, as3, ad3,
                                                hsb3, b3, out);
    #undef GRID
}

// Round 15
// 212.643 us; speedup vs baseline: 1.0530x; 1.0530x over previous
//
#include <hip/hip_runtime.h>
#include <math.h>

static const int NT = 50000, NDAT = 20000, NDEV = 4;
static const int EDT = 800000, EVT = 200000, ETT = 400000;

// scan geometry: 3 graphs x 25 tiles of 2048 (256 thr x 8 elems)
static const int SCAN_TILE = 2048, SCAN_NB = 25;

// fused-front kernel: histogram FIRST (latency-bound waves overlap with compute), then inputs
static const int HT   = EDT + EVT + ETT;     // 1,400,000 hist threads (1 edge each)
static const int IN_A = HT + NDAT * 128;     // conv1 messages, bf16
static const int IN_B = IN_A + NDAT * 4;     // as1
static const int IN_C = IN_B + NT * 4;       // ad1/ad2 (fused)
static const int IN_D = IN_C + NDEV * 128;   // hs2 (fp32)
static const int IN_E = IN_D + NDEV * 4;     // as2
static const int IN_F = IN_E + 256 * 128;    // w3 hi/lo split
static const int FRONT_N = IN_F;

// ---------------- workspace layout (float offsets), liveness-aliased ----------------
// Region R = [OFF_HS, OFF_HS+6.4M): pre-gemm rank/hsb1/rec1; then hsb3 (gemm epilogue).
static const size_t OFF_TASKS = 0;                   // 12,800,000  [NT,256] fp32
static const size_t OFF_HS    = 12800000;            //  6,400,000  region R
static const size_t OFF_RANK  = OFF_HS;              //  1,400,000 ints (dead after permute_w)
static const size_t OFF_HSB1  = OFF_HS + 1400000;    //  1,280,000 floats = 2.56M ushorts
static const size_t OFF_REC1  = OFF_HS + 2680000;    //  3,200,000 floats (800k x 16B) [ends 5,880,000]
static const size_t OFF_HSB3  = OFF_HS;              //  3,200,000 floats = 6.4M ushorts (gemm epilogue)
static const size_t OFF_REC2  = 19200000;            //    800,000 floats (200k x 16B)
static const size_t OFF_REC3  = 20000000;            //  1,600,000 floats (400k x 16B)
static const size_t OFF_DEG   = 23200000;            //    150,000  3 x NT ints
static const size_t OFF_RP    = 23350000;            //    150,003  3 x (NT+1) ints
static const size_t OFF_AS1   = 23500004;            //     80,000
static const size_t OFF_AD1   = 23580004;            //    200,000  as3 reuses
static const size_t OFF_AD2   = 23780004;            //    200,000  ad3 reuses
static const size_t OFF_HS2   = 23980004;            //        512
static const size_t OFF_AS2   = 23980516;            //         16
static const size_t OFF_QS1   = 23980532;            //         32
static const size_t OFF_QD1   = 23980564;            //         64
static const size_t OFF_P1    = 23980628;            //         32
static const size_t OFF_QS2   = 23980660;            //         32
static const size_t OFF_QD2   = 23980692;            //         64
static const size_t OFF_P2    = 23980756;            //         24
static const size_t OFF_P3    = 23980780;            //         16
static const size_t OFF_BSUM  = 23980796;            //        128 ints (75 used, RAW tile sums)
static const size_t OFF_W3HT  = 23980924;            //     16,384 (32768 ushorts, [128n][256k])
static const size_t OFF_W3LT  = 23997308;            //     16,384
static const size_t WS_TOTAL  = 24013692;            // floats (~96 MiB)

typedef short v8s __attribute__((ext_vector_type(8)));
typedef float v4f __attribute__((ext_vector_type(4)));

__device__ __forceinline__ float lrelu(float a) { return a > 0.f ? a : 0.2f * a; }
__device__ __forceinline__ unsigned short f2bf(float x) {
    unsigned int u = __float_as_uint(x);
    return (unsigned short)((u + 0x7FFFu + ((u >> 16) & 1u)) >> 16);
}
__device__ __forceinline__ float bf2f(unsigned short h) {
    return __uint_as_float(((unsigned int)h) << 16);
}
// select the h-th bf16 from the pair of packed words (w0|w1<<16, w2|w3<<16)
__device__ __forceinline__ float bfsel(unsigned int lo01, unsigned int lo23, int h) {
    unsigned int word = (h < 2) ? lo01 : lo23;
    return bf2f((unsigned short)((h & 1) ? (word >> 16) : (word & 0xFFFFu)));
}
__device__ __forceinline__ void cvt_split(const float4& A, const float4& B, v8s& hi, v8s& lo) {
    union { unsigned short u[8]; v8s v; } H, L;
    float f[8] = {A.x, A.y, A.z, A.w, B.x, B.y, B.z, B.w};
    #pragma unroll
    for (int i = 0; i < 8; ++i) {
        unsigned short h = f2bf(f[i]);
        H.u[i] = h;
        L.u[i] = f2bf(f[i] - bf2f(h));
    }
    hi = H.v; lo = L.v;
}

// Q[k][h] = sum_c W[k*128 + h*32 + c] * A[h*32 + c], for all 7 small matrices
__global__ void k_proj_small(const float* Ws1, const float* As1,
                             const float* Wd1, const float* Ad1,
                             const float* We1, const float* Ae1,
                             const float* Ws2, const float* As2,
                             const float* Wd2, const float* Ad2,
                             const float* We2, const float* Ae2,
                             const float* We3, const float* Ae3,
                             float* Qs1, float* Qd1, float* P1,
                             float* Qs2, float* Qd2, float* P2, float* P3) {
    int t = threadIdx.x;
    const float *W, *A; float* O; int u;
    if      (t < 32)  { W = Ws1; A = As1; O = Qs1; u = t; }
    else if (t < 96)  { W = Wd1; A = Ad1; O = Qd1; u = t - 32; }
    else if (t < 128) { W = We1; A = Ae1; O = P1;  u = t - 96; }
    else if (t < 160) { W = Ws2; A = As2; O = Qs2; u = t - 128; }
    else if (t < 224) { W = Wd2; A = Ad2; O = Qd2; u = t - 160; }
    else if (t < 248) { W = We2; A = Ae2; O = P2;  u = t - 224; }
    else if (t < 264) { W = We3; A = Ae3; O = P3;  u = t - 248; }
    else return;
    int k = u >> 2, h = u & 3;
    float acc = 0.f;
    for (int c = 0; c < 32; ++c) acc += W[k * 128 + h * 32 + c] * A[h * 32 + c];
    O[k * 4 + h] = acc;
}

// fused front: 1-edge-per-thread histogram FIRST (overlaps with compute blocks),
// rank word packs (rank<<16 | local_dst) so permute never re-reads the dst arrays;
// then inputs prep (conv1 bf16 msgs, as1, ad1/ad2, hs2, as2, W3 split).
__global__ __launch_bounds__(256) void k_front(const float* __restrict__ x_data,
                                               const float* __restrict__ Ws1,
                                               unsigned short* __restrict__ hsb1,
                                               const float* __restrict__ Qs1,
                                               float* __restrict__ as1,
                                               const float* __restrict__ x_tasks,
                                               const float* __restrict__ Qd1,
                                               const float* __restrict__ Qd2,
                                               float* __restrict__ ad1, float* __restrict__ ad2,
                                               const float* __restrict__ x_dev,
                                               const float* __restrict__ Ws2,
                                               float* __restrict__ hs2,
                                               const float* __restrict__ Qs2,
                                               float* __restrict__ as2,
                                               const float* __restrict__ W3,
                                               unsigned short* __restrict__ w3hT,
                                               unsigned short* __restrict__ w3lT,
                                               const int* __restrict__ dt,
                                               const int* __restrict__ vt,
                                               const int* __restrict__ tt,
                                               int* __restrict__ deg,
                                               int* __restrict__ rank) {
    int idx = blockIdx.x * blockDim.x + threadIdx.x;
    if (idx < HT) {                          // histogram, 1 edge/thread
        if (idx < EDT) {
            int d = dt[EDT + idx];
            int r = atomicAdd(&deg[d], 1);
            rank[idx] = (r << 16) | d;
        } else if (idx < EDT + EVT) {
            int d = vt[EVT + (idx - EDT)];
            int r = atomicAdd(&deg[NT + d], 1);
            rank[idx] = (r << 16) | d;
        } else {
            int d = tt[ETT + (idx - EDT - EVT)];
            int r = atomicAdd(&deg[2 * NT + d], 1);
            rank[idx] = (r << 16) | d;
        }
    } else if (idx < IN_A) {                 // conv1 message table, bf16
        int i = idx - HT;
        int n = i >> 7, j = i & 127;
        float acc = 0.f;
        #pragma unroll
        for (int k = 0; k < 8; ++k) acc += x_data[n * 8 + k] * Ws1[k * 128 + j];
        hsb1[i] = f2bf(acc);
    } else if (idx < IN_B) {                 // as1
        int i = idx - IN_A;
        int n = i >> 2, h = i & 3;
        float acc = 0.f;
        #pragma unroll
        for (int k = 0; k < 8; ++k) acc += x_data[n * 8 + k] * Qs1[k * 4 + h];
        as1[i] = acc;
    } else if (idx < IN_C) {                 // ad1, ad2 (one pass over x_tasks)
        int i = idx - IN_B;
        int n = i >> 2, h = i & 3;
        float a = 0.f, b = 0.f;
        #pragma unroll
        for (int k = 0; k < 16; ++k) {
            float v = x_tasks[n * 16 + k];
            a += v * Qd1[k * 4 + h];
            b += v * Qd2[k * 4 + h];
        }
        ad1[i] = a; ad2[i] = b;
    } else if (idx < IN_D) {                 // hs2 (fp32)
        int i = idx - IN_C;
        int n = i >> 7, j = i & 127;
        float acc = 0.f;
        #pragma unroll
        for (int k = 0; k < 8; ++k) acc += x_dev[n * 8 + k] * Ws2[k * 128 + j];
        hs2[i] = acc;
    } else if (idx < IN_E) {                 // as2
        int i = idx - IN_D;
        int n = i >> 2, h = i & 3;
        float acc = 0.f;
        #pragma unroll
        for (int k = 0; k < 8; ++k) acc += x_dev[n * 8 + k] * Qs2[k * 4 + h];
        as2[i] = acc;
    } else if (idx < IN_F) {                 // W3 split, transposed
        int i = idx - IN_E;
        int k = i >> 7, n = i & 127;
        float x = W3[i];
        unsigned short h = f2bf(x);
        w3hT[n * 256 + k] = h;
        w3lT[n * 256 + k] = f2bf(x - bf2f(h));
    }
}

// scan phase A: per-tile block reduce -> bsum[75] (RAW sums); coalesced int4 loads
__global__ __launch_bounds__(256) void k_scan_part(const int* __restrict__ deg,
                                                   int* __restrict__ bsum) {
    int b = blockIdx.x;
    int g = b / SCAN_NB, t = b % SCAN_NB;
    int base = t * SCAN_TILE + threadIdx.x * 8;
    const int* dg = deg + (size_t)g * NT;
    int s = 0;
    if (base + 8 <= NT) {
        int4 a = *reinterpret_cast<const int4*>(dg + base);
        int4 c = *reinterpret_cast<const int4*>(dg + base + 4);
        s = a.x + a.y + a.z + a.w + c.x + c.y + c.z + c.w;
    } else {
        for (int i = 0; i < 8; ++i) if (base + i < NT) s += dg[base + i];
    }
    __shared__ int red[256];
    red[threadIdx.x] = s;
    __syncthreads();
    for (int off = 128; off > 0; off >>= 1) {
        if (threadIdx.x < off) red[threadIdx.x] += red[threadIdx.x + off];
        __syncthreads();
    }
    if (threadIdx.x == 0) bsum[b] = red[0];
}

// scan phase B (fused): per-tile exclusive scan + redundant 25-entry bsum prefix
__global__ __launch_bounds__(256) void k_scan_final(const int* __restrict__ deg,
                                                    const int* __restrict__ bsum,
                                                    int* __restrict__ rp) {
    int b = blockIdx.x;
    int g = b / SCAN_NB, t = b % SCAN_NB;
    int tid = threadIdx.x;
    int base = t * SCAN_TILE + tid * 8;
    const int* dg = deg + (size_t)g * NT;
    int* rpg = rp + (size_t)g * (NT + 1);
    int v[8];
    int s = 0;
    if (base + 8 <= NT) {
        int4 a = *reinterpret_cast<const int4*>(dg + base);
        int4 c = *reinterpret_cast<const int4*>(dg + base + 4);
        v[0] = a.x; v[1] = a.y; v[2] = a.z; v[3] = a.w;
        v[4] = c.x; v[5] = c.y; v[6] = c.z; v[7] = c.w;
        s = v[0] + v[1] + v[2] + v[3] + v[4] + v[5] + v[6] + v[7];
    } else {
        #pragma unroll
        for (int i = 0; i < 8; ++i) {
            v[i] = (base + i < NT) ? dg[base + i] : 0;
            s += v[i];
        }
    }
    __shared__ int sums[256];
    sums[tid] = s;
    __syncthreads();
    for (int off = 1; off < 256; off <<= 1) {
        int x = (tid >= off) ? sums[tid - off] : 0;
        __syncthreads();
        sums[tid] += x;
        __syncthreads();
    }
    int toff = 0;
    for (int t2 = 0; t2 < t; ++t2) toff += bsum[g * SCAN_NB + t2];
    int run = toff + (tid ? sums[tid - 1] : 0);
    #pragma unroll
    for (int i = 0; i < 8; ++i) {
        int idx = base + i;
        if (idx < NT) {
            rpg[idx] = run; run += v[i];
            if (idx == NT - 1) rpg[NT] = run;
        }
    }
}

// permute + weight precompute: ONE 16B scattered record per edge; dst comes packed
// in the rank word (no dst-array re-read).
// conv1/conv2: {w0..w3 bf16 (8B), src, pad}; conv3: {src, ae0..ae3 bf16 (8B), pad}.
__global__ void k_permute_w(const int* __restrict__ dt, const int* __restrict__ vt,
                            const int* __restrict__ tt, const int* __restrict__ rank,
                            const int* __restrict__ rp,
                            const float* __restrict__ as1, const float* __restrict__ ad1,
                            const float* __restrict__ P1, const float* __restrict__ ea1,
                            const float* __restrict__ as2, const float* __restrict__ ad2,
                            const float* __restrict__ P2, const float* __restrict__ ea2,
                            const float* __restrict__ P3, const float* __restrict__ ea3,
                            uint4* __restrict__ rec1, uint4* __restrict__ rec2,
                            uint4* __restrict__ rec3) {
    int e = blockIdx.x * blockDim.x + threadIdx.x;
    if (e < EDT) {
        int rk = rank[e];
        int d = rk & 0xFFFF;
        int s = dt[e];
        int slot = rp[d] + (rk >> 16);
        float l[4];
        #pragma unroll
        for (int h = 0; h < 4; ++h) l[h] = as1[s * 4 + h] + ad1[d * 4 + h];
        float4 A = *reinterpret_cast<const float4*>(&ea1[(size_t)e * 8]);
        float4 B = *reinterpret_cast<const float4*>(&ea1[(size_t)e * 8 + 4]);
        float ev[8] = {A.x, A.y, A.z, A.w, B.x, B.y, B.z, B.w};
        #pragma unroll
        for (int k = 0; k < 8; ++k)
            #pragma unroll
            for (int h = 0; h < 4; ++h) l[h] += ev[k] * P1[k * 4 + h];
        unsigned int w01 = (unsigned int)f2bf(expf(lrelu(l[0])))
                         | ((unsigned int)f2bf(expf(lrelu(l[1]))) << 16);
        unsigned int w23 = (unsigned int)f2bf(expf(lrelu(l[2])))
                         | ((unsigned int)f2bf(expf(lrelu(l[3]))) << 16);
        rec1[slot] = make_uint4(w01, w23, (unsigned int)s, 0u);
    } else if (e < EDT + EVT) {
        int ee = e - EDT;
        int rk = rank[e];
        int d = rk & 0xFFFF;
        int s = vt[ee];
        int slot = rp[(NT + 1) + d] + (rk >> 16);
        float l[4];
        #pragma unroll
        for (int h = 0; h < 4; ++h) l[h] = as2[s * 4 + h] + ad2[d * 4 + h];
        float2 a = *reinterpret_cast<const float2*>(&ea2[(size_t)ee * 6]);
        float2 b = *reinterpret_cast<const float2*>(&ea2[(size_t)ee * 6 + 2]);
        float2 c = *reinterpret_cast<const float2*>(&ea2[(size_t)ee * 6 + 4]);
        float ev[6] = {a.x, a.y, b.x, b.y, c.x, c.y};
        #pragma unroll
        for (int k = 0; k < 6; ++k)
            #pragma unroll
            for (int h = 0; h < 4; ++h) l[h] += ev[k] * P2[k * 4 + h];
        unsigned int w01 = (unsigned int)f2bf(expf(lrelu(l[0])))
                         | ((unsigned int)f2bf(expf(lrelu(l[1]))) << 16);
        unsigned int w23 = (unsigned int)f2bf(expf(lrelu(l[2])))
                         | ((unsigned int)f2bf(expf(lrelu(l[3]))) << 16);
        rec2[slot] = make_uint4(w01, w23, (unsigned int)s, 0u);
    } else if (e < EDT + EVT + ETT) {
        int ee = e - EDT - EVT;
        int rk = rank[e];
        int d = rk & 0xFFFF;
        int s = tt[ee];
        int slot = rp[2 * (NT + 1) + d] + (rk >> 16);
        float4 q = *reinterpret_cast<const float4*>(&ea3[(size_t)ee * 4]);
        float ae[4];
        #pragma unroll
        for (int h = 0; h < 4; ++h)
            ae[h] = q.x * P3[h] + q.y * P3[4 + h] + q.z * P3[8 + h] + q.w * P3[12 + h];
        unsigned int a01 = (unsigned int)f2bf(ae[0]) | ((unsigned int)f2bf(ae[1]) << 16);
        unsigned int a23 = (unsigned int)f2bf(ae[2]) | ((unsigned int)f2bf(ae[3]) << 16);
        rec3[slot] = make_uint4((unsigned int)s, a01, a23, 0u);
    }
}

// fused conv1+conv2 gathers: block < NT/8 -> conv1 (bf16 msgs); else conv2 (fp32 2KB table)
__global__ __launch_bounds__(256) void k_gather12(const int* __restrict__ rp1,
                                                  const uint4* __restrict__ rec1,
                                                  const unsigned short* __restrict__ hsb,
                                                  const float* __restrict__ b1,
                                                  const int* __restrict__ rp2,
                                                  const uint4* __restrict__ rec2,
                                                  const float* __restrict__ hs2,
                                                  const float* __restrict__ b2,
                                                  float* __restrict__ tasks) {
    int tid = threadIdx.x;
    int lane = tid & 31;
    int h = lane >> 3;
    if (blockIdx.x < NT / 8) {
        int d = blockIdx.x * 8 + (tid >> 5);
        int c0 = (lane & 7) * 4;
        int i0 = rp1[d], i1 = rp1[d + 1];
        float a0 = 0.f, a1 = 0.f, a2 = 0.f, a3 = 0.f, den = 0.f;
        int i = i0;
        for (; i + 4 <= i1; i += 4) {
            uint4 r0 = rec1[i], r1 = rec1[i + 1], r2 = rec1[i + 2], r3 = rec1[i + 3];
            float w0 = bfsel(r0.x, r0.y, h);
            float w1 = bfsel(r1.x, r1.y, h);
            float w2 = bfsel(r2.x, r2.y, h);
            float w3 = bfsel(r3.x, r3.y, h);
            ushort4 m0 = *reinterpret_cast<const ushort4*>(&hsb[(size_t)r0.z * 128 + h * 32 + c0]);
            ushort4 m1 = *reinterpret_cast<const ushort4*>(&hsb[(size_t)r1.z * 128 + h * 32 + c0]);
            ushort4 m2 = *reinterpret_cast<const ushort4*>(&hsb[(size_t)r2.z * 128 + h * 32 + c0]);
            ushort4 m3 = *reinterpret_cast<const ushort4*>(&hsb[(size_t)r3.z * 128 + h * 32 + c0]);
            a0 += w0 * bf2f(m0.x) + w1 * bf2f(m1.x) + w2 * bf2f(m2.x) + w3 * bf2f(m3.x);
            a1 += w0 * bf2f(m0.y) + w1 * bf2f(m1.y) + w2 * bf2f(m2.y) + w3 * bf2f(m3.y);
            a2 += w0 * bf2f(m0.z) + w1 * bf2f(m1.z) + w2 * bf2f(m2.z) + w3 * bf2f(m3.z);
            a3 += w0 * bf2f(m0.w) + w1 * bf2f(m1.w) + w2 * bf2f(m2.w) + w3 * bf2f(m3.w);
            den += w0 + w1 + w2 + w3;
        }
        for (; i < i1; ++i) {
            uint4 r = rec1[i];
            float w = bfsel(r.x, r.y, h);
            ushort4 m = *reinterpret_cast<const ushort4*>(&hsb[(size_t)r.z * 128 + h * 32 + c0]);
            a0 += w * bf2f(m.x); a1 += w * bf2f(m.y);
            a2 += w * bf2f(m.z); a3 += w * bf2f(m.w);
            den += w;
        }
        int j0 = h * 32 + c0;
        float4 b4 = *reinterpret_cast<const float4*>(&b1[j0]);
        float r = 1.f / (den + 1e-16f);
        float4 o = make_float4(fmaxf(a0 * r + b4.x, 0.f), fmaxf(a1 * r + b4.y, 0.f),
                               fmaxf(a2 * r + b4.z, 0.f), fmaxf(a3 * r + b4.w, 0.f));
        *reinterpret_cast<float4*>(&tasks[(size_t)d * 256 + j0]) = o;
    } else {
        int d = (blockIdx.x - NT / 8) * 8 + (tid >> 5);
        int i0 = rp2[d], i1 = rp2[d + 1];
        float ax = 0.f, ay = 0.f, az = 0.f, aw = 0.f, den = 0.f;
        int i = i0;
        for (; i + 4 <= i1; i += 4) {
            uint4 r0 = rec2[i], r1 = rec2[i + 1], r2 = rec2[i + 2], r3 = rec2[i + 3];
            float w0 = bfsel(r0.x, r0.y, h);
            float w1 = bfsel(r1.x, r1.y, h);
            float w2 = bfsel(r2.x, r2.y, h);
            float w3 = bfsel(r3.x, r3.y, h);
            float4 v0 = *reinterpret_cast<const float4*>(&hs2[r0.z * 128 + lane * 4]);
            float4 v1 = *reinterpret_cast<const float4*>(&hs2[r1.z * 128 + lane * 4]);
            float4 v2 = *reinterpret_cast<const float4*>(&hs2[r2.z * 128 + lane * 4]);
            float4 v3 = *reinterpret_cast<const float4*>(&hs2[r3.z * 128 + lane * 4]);
            ax += v0.x * w0 + v1.x * w1 + v2.x * w2 + v3.x * w3;
            ay += v0.y * w0 + v1.y * w1 + v2.y * w2 + v3.y * w3;
            az += v0.z * w0 + v1.z * w1 + v2.z * w2 + v3.z * w3;
            aw += v0.w * w0 + v1.w * w1 + v2.w * w2 + v3.w * w3;
            den += w0 + w1 + w2 + w3;
        }
        for (; i < i1; ++i) {
            uint4 r4 = rec2[i];
            float w = bfsel(r4.x, r4.y, h);
            float4 v = *reinterpret_cast<const float4*>(&hs2[r4.z * 128 + lane * 4]);
            ax += v.x * w; ay += v.y * w; az += v.z * w; aw += v.w * w;
            den += w;
        }
        float4 b4 = *reinterpret_cast<const float4*>(&b2[lane * 4]);
        float r = 1.f / (den + 1e-16f);
        float4 o = make_float4(fmaxf(ax * r + b4.x, 0.f), fmaxf(ay * r + b4.y, 0.f),
                               fmaxf(az * r + b4.z, 0.f), fmaxf(aw * r + b4.w, 0.f));
        *reinterpret_cast<float4*>(&tasks[(size_t)d * 256 + 128 + lane * 4]) = o;
    }
}

// conv3 gather: 16B records carry {src, ae bf16}; per-head softmax + self-loop
// (mean ae); head-mean via shfl_xor; +b3, relu fused. Writes d_out once.
__global__ __launch_bounds__(256) void k_gather_c3(const int* __restrict__ rp,
                                                   const uint4* __restrict__ rec,
                                                   const float* __restrict__ as3,
                                                   const float* __restrict__ ad3,
                                                   const unsigned short* __restrict__ hsb,
                                                   const float* __restrict__ b3,
                                                   float* __restrict__ out) {
    int tid = threadIdx.x;
    int d = blockIdx.x * 8 + (tid >> 5);
    int lane = tid & 31;
    int h = lane >> 3;
    int c0 = (lane & 7) * 4;
    float adv = ad3[d * 4 + h];
    int i0 = rp[d], i1 = rp[d + 1];
    float a0 = 0.f, a1 = 0.f, a2 = 0.f, a3 = 0.f, den = 0.f, aes = 0.f;
    int i = i0;
    for (; i + 4 <= i1; i += 4) {
        uint4 r0 = rec[i], r1 = rec[i + 1], r2 = rec[i + 2], r3 = rec[i + 3];
        float s0 = as3[(size_t)r0.x * 4 + h], s1 = as3[(size_t)r1.x * 4 + h];
        float s2 = as3[(size_t)r2.x * 4 + h], s3 = as3[(size_t)r3.x * 4 + h];
        ushort4 m0 = *reinterpret_cast<const ushort4*>(&hsb[(size_t)r0.x * 128 + h * 32 + c0]);
        ushort4 m1 = *reinterpret_cast<const ushort4*>(&hsb[(size_t)r1.x * 128 + h * 32 + c0]);
        ushort4 m2 = *reinterpret_cast<const ushort4*>(&hsb[(size_t)r2.x * 128 + h * 32 + c0]);
        ushort4 m3 = *reinterpret_cast<const ushort4*>(&hsb[(size_t)r3.x * 128 + h * 32 + c0]);
        float ae0 = bfsel(r0.y, r0.z, h);
        float ae1 = bfsel(r1.y, r1.z, h);
        float ae2 = bfsel(r2.y, r2.z, h);
        float ae3 = bfsel(r3.y, r3.z, h);
        float w0 = expf(lrelu(s0 + adv + ae0));
        float w1 = expf(lrelu(s1 + adv + ae1));
        float w2 = expf(lrelu(s2 + adv + ae2));
        float w3 = expf(lrelu(s3 + adv + ae3));
        a0 += w0 * bf2f(m0.x) + w1 * bf2f(m1.x) + w2 * bf2f(m2.x) + w3 * bf2f(m3.x);
        a1 += w0 * bf2f(m0.y) + w1 * bf2f(m1.y) + w2 * bf2f(m2.y) + w3 * bf2f(m3.y);
        a2 += w0 * bf2f(m0.z) + w1 * bf2f(m1.z) + w2 * bf2f(m2.z) + w3 * bf2f(m3.z);
        a3 += w0 * bf2f(m0.w) + w1 * bf2f(m1.w) + w2 * bf2f(m2.w) + w3 * bf2f(m3.w);
        den += w0 + w1 + w2 + w3;
        aes += ae0 + ae1 + ae2 + ae3;
    }
    for (; i < i1; ++i) {
        uint4 r4 = rec[i];
        float s = as3[(size_t)r4.x * 4 + h];
        ushort4 m = *reinterpret_cast<const ushort4*>(&hsb[(size_t)r4.x * 128 + h * 32 + c0]);
        float ae = bfsel(r4.y, r4.z, h);
        float w = expf(lrelu(s + adv + ae));
        a0 += w * bf2f(m.x); a1 += w * bf2f(m.y);
        a2 += w * bf2f(m.z); a3 += w * bf2f(m.w);
        den += w; aes += ae;
    }
    float cnt = (float)(i1 - i0);
    float mloop = aes / fmaxf(cnt, 1.f);
    float exl = expf(lrelu(as3[(size_t)d * 4 + h] + adv + mloop));
    ushort4 md = *reinterpret_cast<const ushort4*>(&hsb[(size_t)d * 128 + h * 32 + c0]);
    float rden = 1.f / (den + exl + 1e-16f);
    float p0 = (a0 + exl * bf2f(md.x)) * rden;
    float p1 = (a1 + exl * bf2f(md.y)) * rden;
    float p2 = (a2 + exl * bf2f(md.z)) * rden;
    float p3 = (a3 + exl * bf2f(md.w)) * rden;
    p0 += __shfl_xor(p0, 8, 32); p0 += __shfl_xor(p0, 16, 32);
    p1 += __shfl_xor(p1, 8, 32); p1 += __shfl_xor(p1, 16, 32);
    p2 += __shfl_xor(p2, 8, 32); p2 += __shfl_xor(p2, 16, 32);
    p3 += __shfl_xor(p3, 8, 32); p3 += __shfl_xor(p3, 16, 32);
    if ((lane >> 3) == 0) {
        float4 o;
        o.x = fmaxf(0.25f * p0 + b3[c0 + 0], 0.f);
        o.y = fmaxf(0.25f * p1 + b3[c0 + 1], 0.f);
        o.z = fmaxf(0.25f * p2 + b3[c0 + 2], 0.f);
        o.w = fmaxf(0.25f * p3 + b3[c0 + 3], 0.f);
        *reinterpret_cast<float4*>(&out[(size_t)d * 32 + c0]) = o;
    }
}

// hs3 = tasks @ W3 via bf16 split MFMA; epilogue writes hsb3 (bf16) and as3/ad3
// directly from accumulator registers (hs3 fp32 is never materialized).
__global__ __launch_bounds__(256, 2) void k_gemm_mfma(const float* __restrict__ T,
                                                      const unsigned short* __restrict__ w3hT,
                                                      const unsigned short* __restrict__ w3lT,
                                                      const float* __restrict__ As3,
                                                      const float* __restrict__ Ad3,
                                                      unsigned short* __restrict__ hsb,
                                                      float* __restrict__ as3o,
                                                      float* __restrict__ ad3o) {
    __shared__ uint4 sB[2][2048];      // [hi/lo][128 cols x 16 chunks], 64 KiB
    int tid = threadIdx.x;
    int lane = tid & 63;
    int arow = lane & 15;
    int kgrp = lane >> 4;
    int s0 = blockIdx.x * 8 + (tid >> 6) * 2;
    int ss0 = s0 < 3125 ? s0 : 3124;
    int ss1 = (s0 + 1) < 3125 ? (s0 + 1) : 3124;
    const uint4* w3h4 = reinterpret_cast<const uint4*>(w3hT);
    const uint4* w3l4 = reinterpret_cast<const uint4*>(w3lT);

    v4f acc[2][8];
    #pragma unroll
    for (int sp = 0; sp < 2; ++sp)
        #pragma unroll
        for (int nt = 0; nt < 8; ++nt) acc[sp][nt] = (v4f)0.f;

    #pragma unroll
    for (int kt = 0; kt < 2; ++kt) {
        __syncthreads();
        float4 a0[8], a1[8];
        const float* Ta0 = T + (size_t)(ss0 * 16 + arow) * 256 + kt * 128 + kgrp * 8;
        const float* Ta1 = T + (size_t)(ss1 * 16 + arow) * 256 + kt * 128 + kgrp * 8;
        #pragma unroll
        for (int kc = 0; kc < 4; ++kc) {
            a0[kc * 2]     = *reinterpret_cast<const float4*>(Ta0 + kc * 32);
            a0[kc * 2 + 1] = *reinterpret_cast<const float4*>(Ta0 + kc * 32 + 4);
            a1[kc * 2]     = *reinterpret_cast<const float4*>(Ta1 + kc * 32);
            a1[kc * 2 + 1] = *reinterpret_cast<const float4*>(Ta1 + kc * 32 + 4);
        }
        #pragma unroll
        for (int it = 0; it < 8; ++it) {
            int c = it * 256 + tid;
            int n = c >> 4, ch = c & 15;
            int gi = n * 32 + kt * 16 + ch;
            int li = n * 16 + (ch ^ (n & 7));
            sB[0][li] = w3h4[gi];
            sB[1][li] = w3l4[gi];
        }
        __syncthreads();
        #pragma unroll
        for (int kc = 0; kc < 4; ++kc) {
            v8s ah0, al0, ah1, al1;
            cvt_split(a0[kc * 2], a0[kc * 2 + 1], ah0, al0);
            cvt_split(a1[kc * 2], a1[kc * 2 + 1], ah1, al1);
            #pragma unroll
            for (int nt = 0; nt < 8; ++nt) {
                int col = nt * 16 + arow;
                int ch = kc * 4 + kgrp;
                int li = col * 16 + (ch ^ (col & 7));
                v8s bh = *reinterpret_cast<const v8s*>(&sB[0][li]);
                v8s bl = *reinterpret_cast<const v8s*>(&sB[1][li]);
                acc[0][nt] = __builtin_amdgcn_mfma_f32_16x16x32_bf16(ah0, bh, acc[0][nt], 0, 0, 0);
                acc[0][nt] = __builtin_amdgcn_mfma_f32_16x16x32_bf16(ah0, bl, acc[0][nt], 0, 0, 0);
                acc[0][nt] = __builtin_amdgcn_mfma_f32_16x16x32_bf16(al0, bh, acc[0][nt], 0, 0, 0);
                acc[1][nt] = __builtin_amdgcn_mfma_f32_16x16x32_bf16(ah1, bh, acc[1][nt], 0, 0, 0);
                acc[1][nt] = __builtin_amdgcn_mfma_f32_16x16x32_bf16(ah1, bl, acc[1][nt], 0, 0, 0);
                acc[1][nt] = __builtin_amdgcn_mfma_f32_16x16x32_bf16(al1, bh, acc[1][nt], 0, 0, 0);
            }
        }
    }
    // epilogue: bf16 messages + per-row as3/ad3 (16-lane shfl reduction per head)
    float As3v[8], Ad3v[8];
    #pragma unroll
    for (int nt = 0; nt < 8; ++nt) {
        As3v[nt] = As3[nt * 16 + arow];
        Ad3v[nt] = Ad3[nt * 16 + arow];
    }
    #pragma unroll
    for (int sp = 0; sp < 2; ++sp) {
        int s = s0 + sp;
        if (s >= 3125) continue;
        #pragma unroll
        for (int i = 0; i < 4; ++i) {
            int row = s * 16 + kgrp * 4 + i;
            #pragma unroll
            for (int nt = 0; nt < 8; ++nt)
                hsb[(size_t)row * 128 + nt * 16 + arow] = f2bf(acc[sp][nt][i]);
            #pragma unroll
            for (int h = 0; h < 4; ++h) {
                float pa = acc[sp][2 * h][i] * As3v[2 * h] + acc[sp][2 * h + 1][i] * As3v[2 * h + 1];
                float pb = acc[sp][2 * h][i] * Ad3v[2 * h] + acc[sp][2 * h + 1][i] * Ad3v[2 * h + 1];
                #pragma unroll
                for (int off = 1; off < 16; off <<= 1) {
                    pa += __shfl_xor(pa, off, 64);
                    pb += __shfl_xor(pb, off, 64);
                }
                if (arow == 0) {
                    as3o[row * 4 + h] = pa;
                    ad3o[row * 4 + h] = pb;
                }
            }
        }
    }
}

extern "C" void kernel_launch(void* const* d_in, const int* in_sizes, int n_in,
                              void* d_out, int out_size, void* d_ws, size_t ws_size,
                              hipStream_t stream) {
    const float* x_data  = (const float*)d_in[0];
    const float* x_tasks = (const float*)d_in[1];
    const float* x_dev   = (const float*)d_in[2];
    const int*   ei_dt   = (const int*)d_in[3];
    const float* ea_dt   = (const float*)d_in[4];
    const int*   ei_vt   = (const int*)d_in[5];
    const float* ea_vt   = (const float*)d_in[6];
    const int*   ei_tt   = (const int*)d_in[7];
    const float* ea_tt   = (const float*)d_in[8];
    const float* Ws1 = (const float*)d_in[9];  const float* Wd1 = (const float*)d_in[10];
    const float* We1 = (const float*)d_in[11]; const float* As1 = (const float*)d_in[12];
    const float* Ad1 = (const float*)d_in[13]; const float* Ae1 = (const float*)d_in[14];
    const float* b1  = (const float*)d_in[15];
    const float* Ws2 = (const float*)d_in[16]; const float* Wd2 = (const float*)d_in[17];
    const float* We2 = (const float*)d_in[18]; const float* As2 = (const float*)d_in[19];
    const float* Ad2 = (const float*)d_in[20]; const float* Ae2 = (const float*)d_in[21];
    const float* b2  = (const float*)d_in[22];
    const float* W3  = (const float*)d_in[23]; const float* We3 = (const float*)d_in[24];
    const float* As3 = (const float*)d_in[25]; const float* Ad3 = (const float*)d_in[26];
    const float* Ae3 = (const float*)d_in[27]; const float* b3  = (const float*)d_in[28];

    if (ws_size < WS_TOTAL * sizeof(float)) return;

    float* w = (float*)d_ws;
    float* tasks = w + OFF_TASKS;
    int*   rank  = (int*)(w + OFF_RANK);
    unsigned short* hsb1 = (unsigned short*)(w + OFF_HSB1);
    unsigned short* hsb3 = (unsigned short*)(w + OFF_HSB3);  // aliases rank/hsb1/rec1 (dead by gemm)
    uint4* rec1  = (uint4*)(w + OFF_REC1);
    uint4* rec2  = (uint4*)(w + OFF_REC2);
    uint4* rec3  = (uint4*)(w + OFF_REC3);
    int*   deg   = (int*)(w + OFF_DEG);
    int*   rp    = (int*)(w + OFF_RP);
    int*   bsum  = (int*)(w + OFF_BSUM);
    unsigned short* w3hT = (unsigned short*)(w + OFF_W3HT);
    unsigned short* w3lT = (unsigned short*)(w + OFF_W3LT);
    float* as1 = w + OFF_AS1;
    float* ad1 = w + OFF_AD1; float* as3 = w + OFF_AD1;   // as3 aliases ad1 (dead after permute)
    float* ad2 = w + OFF_AD2; float* ad3 = w + OFF_AD2;   // ad3 aliases ad2
    float* hs2 = w + OFF_HS2; float* as2 = w + OFF_AS2;
    float* Qs1 = w + OFF_QS1; float* Qd1 = w + OFF_QD1; float* P1 = w + OFF_P1;
    float* Qs2 = w + OFF_QS2; float* Qd2 = w + OFF_QD2; float* P2 = w + OFF_P2;
    float* P3  = w + OFF_P3;
    float* out = (float*)d_out;

    dim3 B(256);
    #define GRID(n) dim3((unsigned)(((n) + 255) / 256))

    hipMemsetAsync(deg, 0, 3 * NT * sizeof(int), stream);
    k_proj_small<<<1, 320, 0, stream>>>(Ws1, As1, Wd1, Ad1, We1, Ae1,
                                        Ws2, As2, Wd2, Ad2, We2, Ae2, We3, Ae3,
                                        Qs1, Qd1, P1, Qs2, Qd2, P2, P3);
    k_front<<<GRID(FRONT_N), B, 0, stream>>>(x_data, Ws1, hsb1, Qs1, as1,
                                             x_tasks, Qd1, Qd2, ad1, ad2,
                                             x_dev, Ws2, hs2, Qs2, as2,
                                             W3, w3hT, w3lT,
                                             ei_dt, ei_vt, ei_tt, deg, rank);
    k_scan_part<<<dim3(3 * SCAN_NB), B, 0, stream>>>(deg, bsum);
    k_scan_final<<<dim3(3 * SCAN_NB), B, 0, stream>>>(deg, bsum, rp);
    k_permute_w<<<GRID(EDT + EVT + ETT), B, 0, stream>>>(ei_dt, ei_vt, ei_tt, rank, rp,
                                                         as1, ad1, P1, ea_dt,
                                                         as2, ad2, P2, ea_vt,
                                                         P3, ea_tt,
                                                         rec1, rec2, rec3);
    k_gather12<<<dim3(2 * (NT / 8)), B, 0, stream>>>(rp, rec1, hsb1, b1,
                                                     rp + (NT + 1), rec2, hs2, b2, tasks);
    k_gemm_mfma<<<dim3(391), dim3(256), 0, stream>>>(tasks, w3hT, w3lT, As3, Ad3,
                                                     hsb3, as3, ad3);
    k_gather_c3<<<dim3(NT / 8), B, 0, stream>>>(rp + 2 * (NT + 1), rec3, as3, ad3,
                                                hsb3, b3, out);
    #undef GRID
}